// Round 2
// baseline (3438.800 us; speedup 1.0000x reference)
//
#include <hip/hip_runtime.h>
#include <stdint.h>

#define N_NODES 100000
#define N_EDGES 600000
#define HID 128
#define OUT_C 64
#define HALF_ELEMS 6400000   // 50000*128
#define NELEMS 12800000      // 100000*128
#define BN_EPS 1e-5f

// ---------------- threefry2x32 (matches JAX) ----------------
__device__ __host__ __forceinline__ void threefry2x32(uint32_t k0, uint32_t k1,
                                                      uint32_t x0, uint32_t x1,
                                                      uint32_t& o0, uint32_t& o1) {
  uint32_t ks0 = k0, ks1 = k1, ks2 = k0 ^ k1 ^ 0x1BD11BDAu;
  x0 += ks0; x1 += ks1;
#define TFR(r) { x0 += x1; x1 = (x1 << (r)) | (x1 >> (32 - (r))); x1 ^= x0; }
  TFR(13) TFR(15) TFR(26) TFR(6)
  x0 += ks1; x1 += ks2 + 1u;
  TFR(17) TFR(29) TFR(16) TFR(24)
  x0 += ks2; x1 += ks0 + 2u;
  TFR(13) TFR(15) TFR(26) TFR(6)
  x0 += ks0; x1 += ks1 + 3u;
  TFR(17) TFR(29) TFR(16) TFR(24)
  x0 += ks1; x1 += ks2 + 4u;
  TFR(13) TFR(15) TFR(26) TFR(6)
  x0 += ks2; x1 += ks0 + 5u;
#undef TFR
  o0 = x0; o1 = x1;
}

// JAX threefry_partitionable random_bits for a flat index i (< 2^32):
// bits(i) = out0 ^ out1 of threefry(key, (hi=0, lo=i))
__device__ __forceinline__ uint32_t jax_bits32(uint32_t k0, uint32_t k1, uint32_t i) {
  uint32_t b0, b1;
  threefry2x32(k0, k1, 0u, i, b0, b1);
  return b0 ^ b1;
}

// ---------------- GEMM: O[r][c] = sum_k A[r][k]*W[k][c]; A [nrows][128], W [128][128]
// block = 256 threads (4 waves), 32 rows per block, K split in 2 halves of 64.
// LDS: W-half [64][128] (32KB) + A-transposed [64][36-pad] (~9KB)
__global__ __launch_bounds__(256) void gemm_nk128(const float* __restrict__ A,
                                                  const float* __restrict__ W,
                                                  float* __restrict__ O) {
  __shared__ __align__(16) float Wl[64 * 128];
  __shared__ __align__(16) float At[64 * 36];
  const int tid = threadIdx.x;
  const int lane = tid & 63;
  const int wv = tid >> 6;
  const int rbase = blockIdx.x * 32;
  const int r0 = wv * 8;

  float acc0[8], acc1[8];
#pragma unroll
  for (int i = 0; i < 8; ++i) { acc0[i] = 0.f; acc1[i] = 0.f; }

  for (int kh = 0; kh < 2; ++kh) {
    // stage W half: linear 8192-float copy
    const float4* Wsrc = (const float4*)(W + kh * 64 * 128);
    float4* Wd = (float4*)Wl;
#pragma unroll
    for (int i = 0; i < 8; ++i) Wd[tid + i * 256] = Wsrc[tid + i * 256];
    // stage A-transposed: At[k][row]
#pragma unroll
    for (int i = 0; i < 2; ++i) {
      int f4 = tid + i * 256;           // 512 float4 total
      int row = f4 >> 4;                // 16 float4 per row
      int kq = f4 & 15;
      float4 v = *(const float4*)(A + (size_t)(rbase + row) * 128 + kh * 64 + kq * 4);
      At[(kq * 4 + 0) * 36 + row] = v.x;
      At[(kq * 4 + 1) * 36 + row] = v.y;
      At[(kq * 4 + 2) * 36 + row] = v.z;
      At[(kq * 4 + 3) * 36 + row] = v.w;
    }
    __syncthreads();
#pragma unroll 4
    for (int k = 0; k < 64; ++k) {
      float4 alo = *(const float4*)&At[k * 36 + r0];
      float4 ahi = *(const float4*)&At[k * 36 + r0 + 4];
      float2 w = *(const float2*)&Wl[k * 128 + lane * 2];
      acc0[0] += alo.x * w.x; acc1[0] += alo.x * w.y;
      acc0[1] += alo.y * w.x; acc1[1] += alo.y * w.y;
      acc0[2] += alo.z * w.x; acc1[2] += alo.z * w.y;
      acc0[3] += alo.w * w.x; acc1[3] += alo.w * w.y;
      acc0[4] += ahi.x * w.x; acc1[4] += ahi.x * w.y;
      acc0[5] += ahi.y * w.x; acc1[5] += ahi.y * w.y;
      acc0[6] += ahi.z * w.x; acc1[6] += ahi.z * w.y;
      acc0[7] += ahi.w * w.x; acc1[7] += ahi.w * w.y;
    }
    __syncthreads();
  }
#pragma unroll
  for (int i = 0; i < 8; ++i) {
    int row = rbase + r0 + i;
    float2 v = make_float2(acc0[i], acc1[i]);
    *(float2*)(O + (size_t)row * 128 + lane * 2) = v;
  }
}

// ---------------- AGG[n][c] = b[c]
__global__ __launch_bounds__(256) void init_bias(float* __restrict__ AGG,
                                                 const float* __restrict__ b) {
  int i = blockIdx.x * 256 + threadIdx.x;        // over NELEMS/4 float4s
  float4 bv = ((const float4*)b)[i & 31];
  ((float4*)AGG)[i] = bv;
}

// ---------------- scatter: AGG[dst] += w * H[src]; 32 threads per edge (float4 each)
__global__ __launch_bounds__(256) void scatter_add(const float* __restrict__ H,
                                                   const int* __restrict__ ei,
                                                   const float* __restrict__ ew,
                                                   float* __restrict__ AGG) {
  long idx = (long)blockIdx.x * 256 + threadIdx.x;
  int e = (int)(idx >> 5);
  int q = (int)(idx & 31);
  int s = ei[e];
  int d = ei[e + N_EDGES];
  float w = ew[e];
  float4 v = *(const float4*)(H + (size_t)s * 128 + q * 4);
  float* o = AGG + (size_t)d * 128 + q * 4;
  unsafeAtomicAdd(o + 0, v.x * w);
  unsafeAtomicAdd(o + 1, v.y * w);
  unsafeAtomicAdd(o + 2, v.z * w);
  unsafeAtomicAdd(o + 3, v.w * w);
}

// ---------------- per-channel sum & sumsq
__global__ __launch_bounds__(256) void bn_stats(const float* __restrict__ H,
                                                float* __restrict__ sums) {
  int tid = threadIdx.x;
  int c = tid & 127;
  int part = tid >> 7;
  float s = 0.f, s2 = 0.f;
  for (int row = blockIdx.x * 2 + part; row < N_NODES; row += gridDim.x * 2) {
    float v = H[(size_t)row * 128 + c];
    s += v; s2 += v * v;
  }
  __shared__ float ls[256], ls2[256];
  ls[tid] = s; ls2[tid] = s2;
  __syncthreads();
  if (tid < 128) {
    unsafeAtomicAdd(&sums[c], ls[tid] + ls[tid + 128]);
    unsafeAtomicAdd(&sums[128 + c], ls2[tid] + ls2[tid + 128]);
  }
}

// ---------------- BN(train) + ReLU -> X;  dropout(X) -> HD (JAX partitionable threefry)
__global__ __launch_bounds__(256) void bn_relu_dropout(const float* __restrict__ AGG,
                                                       const float* __restrict__ sums,
                                                       const float* __restrict__ g,
                                                       const float* __restrict__ bt,
                                                       float* __restrict__ X,
                                                       float* __restrict__ HD,
                                                       uint32_t k0, uint32_t k1) {
  int i = blockIdx.x * 256 + threadIdx.x;   // [0, HALF_ELEMS)
  int c = i & 127;
  float mu = sums[c] * (1.0f / N_NODES);
  float var = fmaxf(sums[128 + c] * (1.0f / N_NODES) - mu * mu, 0.f);
  float inv = rsqrtf(var + BN_EPS);
  float gc = g[c], bc = bt[c];
  float a0 = AGG[i];
  float a1 = AGG[i + HALF_ELEMS];
  float y0 = fmaxf(gc * (a0 - mu) * inv + bc, 0.f);
  float y1 = fmaxf(gc * (a1 - mu) * inv + bc, 0.f);
  X[i] = y0;
  X[i + HALF_ELEMS] = y1;
  // partitionable: bits(i) = out0^out1 of threefry(key, (0, i)); keep <=> top bit 0
  uint32_t m0 = jax_bits32(k0, k1, (uint32_t)i);
  uint32_t m1 = jax_bits32(k0, k1, (uint32_t)(i + HALF_ELEMS));
  HD[i] = (m0 & 0x80000000u) ? 0.f : 2.f * y0;
  HD[i + HALF_ELEMS] = (m1 & 0x80000000u) ? 0.f : 2.f * y1;
}

// ---------------- jk = max(x1,x2,x3); OUT = log_softmax(jk @ Wf + bf)
// block 256 = 4 waves; 16 rows/block; wave w handles rows {w, w+4, w+8, w+12}; lane = col
__global__ __launch_bounds__(256) void jk_final(const float* __restrict__ X1,
                                                const float* __restrict__ X2,
                                                const float* __restrict__ X3,
                                                const float* __restrict__ Wf,
                                                const float* __restrict__ bf,
                                                float* __restrict__ OUT) {
  __shared__ __align__(16) float Wl[128 * 64];
  __shared__ __align__(16) float Jl[16][128];
  int tid = threadIdx.x;
  int lane = tid & 63;
  int wv = tid >> 6;
  int rbase = blockIdx.x * 16;
  {
    const float4* ws = (const float4*)Wf;
    float4* wd = (float4*)Wl;
#pragma unroll
    for (int i = 0; i < 8; ++i) wd[tid + i * 256] = ws[tid + i * 256];
  }
#pragma unroll
  for (int i = 0; i < 2; ++i) {
    int f4 = tid + i * 256;       // 512 float4
    int row = f4 >> 5;            // 32 float4 per row
    int q = f4 & 31;
    size_t off = (size_t)(rbase + row) * 128 + q * 4;
    float4 a = *(const float4*)(X1 + off);
    float4 b = *(const float4*)(X2 + off);
    float4 c = *(const float4*)(X3 + off);
    float4 m;
    m.x = fmaxf(fmaxf(a.x, b.x), c.x);
    m.y = fmaxf(fmaxf(a.y, b.y), c.y);
    m.z = fmaxf(fmaxf(a.z, b.z), c.z);
    m.w = fmaxf(fmaxf(a.w, b.w), c.w);
    *(float4*)&Jl[row][q * 4] = m;
  }
  __syncthreads();
  float acc[4];
  float bv = bf[lane];
#pragma unroll
  for (int j = 0; j < 4; ++j) acc[j] = bv;
#pragma unroll 4
  for (int k = 0; k < 128; k += 4) {
    float4 j0 = *(const float4*)&Jl[wv][k];
    float4 j1 = *(const float4*)&Jl[wv + 4][k];
    float4 j2 = *(const float4*)&Jl[wv + 8][k];
    float4 j3 = *(const float4*)&Jl[wv + 12][k];
#pragma unroll
    for (int kk = 0; kk < 4; ++kk) {
      float w = Wl[(k + kk) * 64 + lane];
      acc[0] += ((const float*)&j0)[kk] * w;
      acc[1] += ((const float*)&j1)[kk] * w;
      acc[2] += ((const float*)&j2)[kk] * w;
      acc[3] += ((const float*)&j3)[kk] * w;
    }
  }
#pragma unroll
  for (int j = 0; j < 4; ++j) {
    float v = acc[j];
    float m = v;
#pragma unroll
    for (int s = 32; s > 0; s >>= 1) m = fmaxf(m, __shfl_xor(m, s));
    float e = expf(v - m);
    float sum = e;
#pragma unroll
    for (int s = 32; s > 0; s >>= 1) sum += __shfl_xor(sum, s);
    OUT[(size_t)(rbase + wv + 4 * j) * 64 + lane] = v - m - logf(sum);
  }
}

extern "C" void kernel_launch(void* const* d_in, const int* in_sizes, int n_in,
                              void* d_out, int out_size, void* d_ws, size_t ws_size,
                              hipStream_t stream) {
  const float* x   = (const float*)d_in[0];
  const int*   ei  = (const int*)d_in[1];
  const float* ew  = (const float*)d_in[2];
  const float* W1  = (const float*)d_in[3];
  const float* b1  = (const float*)d_in[4];
  const float* W2  = (const float*)d_in[5];
  const float* b2  = (const float*)d_in[6];
  const float* W3  = (const float*)d_in[7];
  const float* b3  = (const float*)d_in[8];
  const float* g1  = (const float*)d_in[9];
  const float* bt1 = (const float*)d_in[10];
  const float* g2  = (const float*)d_in[11];
  const float* bt2 = (const float*)d_in[12];
  const float* Wf  = (const float*)d_in[13];
  const float* bfb = (const float*)d_in[14];
  float* out = (float*)d_out;

  float* B0 = (float*)d_ws;
  float* B1 = B0 + NELEMS;
  float* B2 = B1 + NELEMS;
  float* B3 = B2 + NELEMS;
  float* sums = B3 + NELEMS;   // 256 floats

  // JAX partitionable split: dk = key(42) -> (0,42);
  // k_i = full threefry output pair at counter (hi=0, lo=i)
  uint32_t k1_0, k1_1, k2_0, k2_1;
  threefry2x32(0u, 42u, 0u, 0u, k1_0, k1_1);
  threefry2x32(0u, 42u, 0u, 1u, k2_0, k2_1);

  const int GEMM_GRID = N_NODES / 32;          // 3125
  const int INIT_GRID = NELEMS / 4 / 256;      // 12500
  const int SCAT_GRID = (N_EDGES * 32) / 256;  // 75000
  const int BN_GRID   = 512;
  const int APPLY_GRID = HALF_ELEMS / 256;     // 25000
  const int FINAL_GRID = N_NODES / 16;         // 6250

  // ---- layer 1
  gemm_nk128<<<GEMM_GRID, 256, 0, stream>>>(x, W1, B0);
  init_bias<<<INIT_GRID, 256, 0, stream>>>(B1, b1);
  scatter_add<<<SCAT_GRID, 256, 0, stream>>>(B0, ei, ew, B1);
  hipMemsetAsync(sums, 0, 256 * sizeof(float), stream);
  bn_stats<<<BN_GRID, 256, 0, stream>>>(B1, sums);
  bn_relu_dropout<<<APPLY_GRID, 256, 0, stream>>>(B1, sums, g1, bt1, B2, B0, k1_0, k1_1);
  // ---- layer 2
  gemm_nk128<<<GEMM_GRID, 256, 0, stream>>>(B0, W2, B1);
  init_bias<<<INIT_GRID, 256, 0, stream>>>(B0, b2);
  scatter_add<<<SCAT_GRID, 256, 0, stream>>>(B1, ei, ew, B0);
  hipMemsetAsync(sums, 0, 256 * sizeof(float), stream);
  bn_stats<<<BN_GRID, 256, 0, stream>>>(B0, sums);
  bn_relu_dropout<<<APPLY_GRID, 256, 0, stream>>>(B0, sums, g2, bt2, B3, B1, k2_0, k2_1);
  // ---- layer 3
  gemm_nk128<<<GEMM_GRID, 256, 0, stream>>>(B1, W3, B0);
  init_bias<<<INIT_GRID, 256, 0, stream>>>(B1, b3);
  scatter_add<<<SCAT_GRID, 256, 0, stream>>>(B0, ei, ew, B1);
  // ---- JK max + final linear + log_softmax
  jk_final<<<FINAL_GRID, 256, 0, stream>>>(B2, B3, B1, Wf, bfb, out);
}

// Round 3
// 606.144 us; speedup vs baseline: 5.6732x; 5.6732x over previous
//
#include <hip/hip_runtime.h>
#include <stdint.h>

#define N_NODES 100000
#define N_EDGES 600000
#define HID 128
#define OUT_C 64
#define HALF_ELEMS 6400000   // 50000*128
#define NELEMS 12800000      // 100000*128
#define BN_EPS 1e-5f

// ---------------- threefry2x32 (matches JAX) ----------------
__device__ __host__ __forceinline__ void threefry2x32(uint32_t k0, uint32_t k1,
                                                      uint32_t x0, uint32_t x1,
                                                      uint32_t& o0, uint32_t& o1) {
  uint32_t ks0 = k0, ks1 = k1, ks2 = k0 ^ k1 ^ 0x1BD11BDAu;
  x0 += ks0; x1 += ks1;
#define TFR(r) { x0 += x1; x1 = (x1 << (r)) | (x1 >> (32 - (r))); x1 ^= x0; }
  TFR(13) TFR(15) TFR(26) TFR(6)
  x0 += ks1; x1 += ks2 + 1u;
  TFR(17) TFR(29) TFR(16) TFR(24)
  x0 += ks2; x1 += ks0 + 2u;
  TFR(13) TFR(15) TFR(26) TFR(6)
  x0 += ks0; x1 += ks1 + 3u;
  TFR(17) TFR(29) TFR(16) TFR(24)
  x0 += ks1; x1 += ks2 + 4u;
  TFR(13) TFR(15) TFR(26) TFR(6)
  x0 += ks2; x1 += ks0 + 5u;
#undef TFR
  o0 = x0; o1 = x1;
}

// JAX threefry_partitionable random_bits for flat index i: out0^out1 of threefry(key,(0,i))
__device__ __forceinline__ uint32_t jax_bits32(uint32_t k0, uint32_t k1, uint32_t i) {
  uint32_t b0, b1;
  threefry2x32(k0, k1, 0u, i, b0, b1);
  return b0 ^ b1;
}

// ---------------- GEMM: O[r][c] = sum_k A[r][k]*W[k][c]
__global__ __launch_bounds__(256) void gemm_nk128(const float* __restrict__ A,
                                                  const float* __restrict__ W,
                                                  float* __restrict__ O) {
  __shared__ __align__(16) float Wl[64 * 128];
  __shared__ __align__(16) float At[64 * 36];
  const int tid = threadIdx.x;
  const int lane = tid & 63;
  const int wv = tid >> 6;
  const int rbase = blockIdx.x * 32;
  const int r0 = wv * 8;

  float acc0[8], acc1[8];
#pragma unroll
  for (int i = 0; i < 8; ++i) { acc0[i] = 0.f; acc1[i] = 0.f; }

  for (int kh = 0; kh < 2; ++kh) {
    const float4* Wsrc = (const float4*)(W + kh * 64 * 128);
    float4* Wd = (float4*)Wl;
#pragma unroll
    for (int i = 0; i < 8; ++i) Wd[tid + i * 256] = Wsrc[tid + i * 256];
#pragma unroll
    for (int i = 0; i < 2; ++i) {
      int f4 = tid + i * 256;
      int row = f4 >> 4;
      int kq = f4 & 15;
      float4 v = *(const float4*)(A + (size_t)(rbase + row) * 128 + kh * 64 + kq * 4);
      At[(kq * 4 + 0) * 36 + row] = v.x;
      At[(kq * 4 + 1) * 36 + row] = v.y;
      At[(kq * 4 + 2) * 36 + row] = v.z;
      At[(kq * 4 + 3) * 36 + row] = v.w;
    }
    __syncthreads();
#pragma unroll 4
    for (int k = 0; k < 64; ++k) {
      float4 alo = *(const float4*)&At[k * 36 + r0];
      float4 ahi = *(const float4*)&At[k * 36 + r0 + 4];
      float2 w = *(const float2*)&Wl[k * 128 + lane * 2];
      acc0[0] += alo.x * w.x; acc1[0] += alo.x * w.y;
      acc0[1] += alo.y * w.x; acc1[1] += alo.y * w.y;
      acc0[2] += alo.z * w.x; acc1[2] += alo.z * w.y;
      acc0[3] += alo.w * w.x; acc1[3] += alo.w * w.y;
      acc0[4] += ahi.x * w.x; acc1[4] += ahi.x * w.y;
      acc0[5] += ahi.y * w.x; acc1[5] += ahi.y * w.y;
      acc0[6] += ahi.z * w.x; acc1[6] += ahi.z * w.y;
      acc0[7] += ahi.w * w.x; acc1[7] += ahi.w * w.y;
    }
    __syncthreads();
  }
#pragma unroll
  for (int i = 0; i < 8; ++i) {
    int row = rbase + r0 + i;
    float2 v = make_float2(acc0[i], acc1[i]);
    *(float2*)(O + (size_t)row * 128 + lane * 2) = v;
  }
}

// ---------------- CSR build ----------------
__global__ __launch_bounds__(256) void csr_count(const int* __restrict__ ei,
                                                 int* __restrict__ cnt) {
  int e = blockIdx.x * 256 + threadIdx.x;
  if (e < N_EDGES) atomicAdd(&cnt[ei[e + N_EDGES]], 1);
}

// block-local exclusive scan of cnt (in place), block totals to bsum
__global__ __launch_bounds__(256) void scan_blocks(int* __restrict__ cnt,
                                                   int* __restrict__ bsum) {
  __shared__ int tmp[256];
  int tid = threadIdx.x;
  int i = blockIdx.x * 256 + tid;
  int v = (i < N_NODES) ? cnt[i] : 0;
  tmp[tid] = v;
  __syncthreads();
  for (int off = 1; off < 256; off <<= 1) {
    int t = (tid >= off) ? tmp[tid - off] : 0;
    __syncthreads();
    if (tid >= off) tmp[tid] += t;
    __syncthreads();
  }
  if (i < N_NODES) cnt[i] = tmp[tid] - v;           // exclusive within block
  if (tid == 255) bsum[blockIdx.x] = tmp[255];
}

// single block: exclusive scan of nb block sums (nb <= 512)
__global__ __launch_bounds__(512) void scan_bsum(int* __restrict__ bsum, int nb) {
  __shared__ int tmp[512];
  int tid = threadIdx.x;
  int v = (tid < nb) ? bsum[tid] : 0;
  tmp[tid] = v;
  __syncthreads();
  for (int off = 1; off < 512; off <<= 1) {
    int t = (tid >= off) ? tmp[tid - off] : 0;
    __syncthreads();
    if (tid >= off) tmp[tid] += t;
    __syncthreads();
  }
  if (tid < nb) bsum[tid] = tmp[tid] - v;           // exclusive
}

__global__ __launch_bounds__(256) void add_offsets(int* __restrict__ cnt,
                                                   const int* __restrict__ bsum,
                                                   int* __restrict__ row_ptr) {
  int i = blockIdx.x * 256 + threadIdx.x;
  if (i < N_NODES) {
    int r = cnt[i] + bsum[blockIdx.x];
    row_ptr[i] = r;
    cnt[i] = r;                                      // cnt becomes the fill cursor
  }
  if (i == 0) row_ptr[N_NODES] = N_EDGES;
}

__global__ __launch_bounds__(256) void csr_fill(const int* __restrict__ ei,
                                                const float* __restrict__ ew,
                                                int* __restrict__ cursor,
                                                int* __restrict__ srcs,
                                                float* __restrict__ wcsr) {
  int e = blockIdx.x * 256 + threadIdx.x;
  if (e < N_EDGES) {
    int d = ei[e + N_EDGES];
    int p = atomicAdd(&cursor[d], 1);
    srcs[p] = ei[e];
    wcsr[p] = ew[e];
  }
}

// ---------------- gather aggregation: AGG[n] = b + sum_{e->n} w_e * H[src_e]
// one wave per node; lane holds channels {2*lane, 2*lane+1}
__global__ __launch_bounds__(256) void gather_agg(const float* __restrict__ H,
                                                  const int* __restrict__ row_ptr,
                                                  const int* __restrict__ srcs,
                                                  const float* __restrict__ wcsr,
                                                  const float* __restrict__ bias,
                                                  float* __restrict__ AGG) {
  int node = blockIdx.x * 4 + (threadIdx.x >> 6);
  int lane = threadIdx.x & 63;
  int beg = row_ptr[node];
  int end = row_ptr[node + 1];
  float2 acc = *(const float2*)(bias + lane * 2);
  int j = beg;
  for (; j + 1 < end; j += 2) {
    int s0 = srcs[j], s1 = srcs[j + 1];
    float w0 = wcsr[j], w1 = wcsr[j + 1];
    float2 v0 = *(const float2*)(H + (size_t)s0 * 128 + lane * 2);
    float2 v1 = *(const float2*)(H + (size_t)s1 * 128 + lane * 2);
    acc.x += w0 * v0.x + w1 * v1.x;
    acc.y += w0 * v0.y + w1 * v1.y;
  }
  if (j < end) {
    int s = srcs[j];
    float w = wcsr[j];
    float2 v = *(const float2*)(H + (size_t)s * 128 + lane * 2);
    acc.x += w * v.x;
    acc.y += w * v.y;
  }
  *(float2*)(AGG + (size_t)node * 128 + lane * 2) = acc;
}

// ---------------- per-channel sum & sumsq
__global__ __launch_bounds__(256) void bn_stats(const float* __restrict__ H,
                                                float* __restrict__ sums) {
  int tid = threadIdx.x;
  int c = tid & 127;
  int part = tid >> 7;
  float s = 0.f, s2 = 0.f;
  for (int row = blockIdx.x * 2 + part; row < N_NODES; row += gridDim.x * 2) {
    float v = H[(size_t)row * 128 + c];
    s += v; s2 += v * v;
  }
  __shared__ float ls[256], ls2[256];
  ls[tid] = s; ls2[tid] = s2;
  __syncthreads();
  if (tid < 128) {
    unsafeAtomicAdd(&sums[c], ls[tid] + ls[tid + 128]);
    unsafeAtomicAdd(&sums[128 + c], ls2[tid] + ls2[tid + 128]);
  }
}

// ---------------- BN(train) + ReLU -> X;  dropout -> HD
__global__ __launch_bounds__(256) void bn_relu_dropout(const float* __restrict__ AGG,
                                                       const float* __restrict__ sums,
                                                       const float* __restrict__ g,
                                                       const float* __restrict__ bt,
                                                       float* __restrict__ X,
                                                       float* __restrict__ HD,
                                                       uint32_t k0, uint32_t k1) {
  int i = blockIdx.x * 256 + threadIdx.x;   // [0, HALF_ELEMS)
  int c = i & 127;
  float mu = sums[c] * (1.0f / N_NODES);
  float var = fmaxf(sums[128 + c] * (1.0f / N_NODES) - mu * mu, 0.f);
  float inv = rsqrtf(var + BN_EPS);
  float gc = g[c], bc = bt[c];
  float a0 = AGG[i];
  float a1 = AGG[i + HALF_ELEMS];
  float y0 = fmaxf(gc * (a0 - mu) * inv + bc, 0.f);
  float y1 = fmaxf(gc * (a1 - mu) * inv + bc, 0.f);
  X[i] = y0;
  X[i + HALF_ELEMS] = y1;
  uint32_t m0 = jax_bits32(k0, k1, (uint32_t)i);
  uint32_t m1 = jax_bits32(k0, k1, (uint32_t)(i + HALF_ELEMS));
  HD[i] = (m0 & 0x80000000u) ? 0.f : 2.f * y0;
  HD[i + HALF_ELEMS] = (m1 & 0x80000000u) ? 0.f : 2.f * y1;
}

// ---------------- jk = max(x1,x2,x3); OUT = log_softmax(jk @ Wf + bf)
__global__ __launch_bounds__(256) void jk_final(const float* __restrict__ X1,
                                                const float* __restrict__ X2,
                                                const float* __restrict__ X3,
                                                const float* __restrict__ Wf,
                                                const float* __restrict__ bf,
                                                float* __restrict__ OUT) {
  __shared__ __align__(16) float Wl[128 * 64];
  __shared__ __align__(16) float Jl[16][128];
  int tid = threadIdx.x;
  int lane = tid & 63;
  int wv = tid >> 6;
  int rbase = blockIdx.x * 16;
  {
    const float4* ws = (const float4*)Wf;
    float4* wd = (float4*)Wl;
#pragma unroll
    for (int i = 0; i < 8; ++i) wd[tid + i * 256] = ws[tid + i * 256];
  }
#pragma unroll
  for (int i = 0; i < 2; ++i) {
    int f4 = tid + i * 256;
    int row = f4 >> 5;
    int q = f4 & 31;
    size_t off = (size_t)(rbase + row) * 128 + q * 4;
    float4 a = *(const float4*)(X1 + off);
    float4 b = *(const float4*)(X2 + off);
    float4 c = *(const float4*)(X3 + off);
    float4 m;
    m.x = fmaxf(fmaxf(a.x, b.x), c.x);
    m.y = fmaxf(fmaxf(a.y, b.y), c.y);
    m.z = fmaxf(fmaxf(a.z, b.z), c.z);
    m.w = fmaxf(fmaxf(a.w, b.w), c.w);
    *(float4*)&Jl[row][q * 4] = m;
  }
  __syncthreads();
  float acc[4];
  float bv = bf[lane];
#pragma unroll
  for (int j = 0; j < 4; ++j) acc[j] = bv;
#pragma unroll 4
  for (int k = 0; k < 128; k += 4) {
    float4 j0 = *(const float4*)&Jl[wv][k];
    float4 j1 = *(const float4*)&Jl[wv + 4][k];
    float4 j2 = *(const float4*)&Jl[wv + 8][k];
    float4 j3 = *(const float4*)&Jl[wv + 12][k];
#pragma unroll
    for (int kk = 0; kk < 4; ++kk) {
      float w = Wl[(k + kk) * 64 + lane];
      acc[0] += ((const float*)&j0)[kk] * w;
      acc[1] += ((const float*)&j1)[kk] * w;
      acc[2] += ((const float*)&j2)[kk] * w;
      acc[3] += ((const float*)&j3)[kk] * w;
    }
  }
#pragma unroll
  for (int j = 0; j < 4; ++j) {
    float v = acc[j];
    float m = v;
#pragma unroll
    for (int s = 32; s > 0; s >>= 1) m = fmaxf(m, __shfl_xor(m, s));
    float e = expf(v - m);
    float sum = e;
#pragma unroll
    for (int s = 32; s > 0; s >>= 1) sum += __shfl_xor(sum, s);
    OUT[(size_t)(rbase + wv + 4 * j) * 64 + lane] = v - m - logf(sum);
  }
}

extern "C" void kernel_launch(void* const* d_in, const int* in_sizes, int n_in,
                              void* d_out, int out_size, void* d_ws, size_t ws_size,
                              hipStream_t stream) {
  const float* x   = (const float*)d_in[0];
  const int*   ei  = (const int*)d_in[1];
  const float* ew  = (const float*)d_in[2];
  const float* W1  = (const float*)d_in[3];
  const float* b1  = (const float*)d_in[4];
  const float* W2  = (const float*)d_in[5];
  const float* b2  = (const float*)d_in[6];
  const float* W3  = (const float*)d_in[7];
  const float* b3  = (const float*)d_in[8];
  const float* g1  = (const float*)d_in[9];
  const float* bt1 = (const float*)d_in[10];
  const float* g2  = (const float*)d_in[11];
  const float* bt2 = (const float*)d_in[12];
  const float* Wf  = (const float*)d_in[13];
  const float* bfb = (const float*)d_in[14];
  float* out = (float*)d_out;

  float* B0 = (float*)d_ws;
  float* B1 = B0 + NELEMS;
  float* B2 = B1 + NELEMS;
  float* B3 = B2 + NELEMS;
  float* sums = B3 + NELEMS;               // 256 floats
  int* cursor = (int*)(sums + 256);        // N_NODES (doubles as cnt/scan buffer)
  int* row_ptr = cursor + N_NODES;         // N_NODES+1
  int* bsum = row_ptr + N_NODES + 1;       // 512
  int* srcs = bsum + 512;                  // N_EDGES
  float* wcsr = (float*)(srcs + N_EDGES);  // N_EDGES

  // JAX partitionable split of key(42)=(0,42): k_i = threefry(key, (0,i)) full pair
  uint32_t k1_0, k1_1, k2_0, k2_1;
  threefry2x32(0u, 42u, 0u, 0u, k1_0, k1_1);
  threefry2x32(0u, 42u, 0u, 1u, k2_0, k2_1);

  const int GEMM_GRID = N_NODES / 32;              // 3125
  const int EDGE_GRID = (N_EDGES + 255) / 256;     // 2344
  const int NODE_GRID = (N_NODES + 255) / 256;     // 391
  const int AGG_GRID  = N_NODES / 4;               // 25000
  const int BN_GRID   = 512;
  const int APPLY_GRID = HALF_ELEMS / 256;         // 25000
  const int FINAL_GRID = N_NODES / 16;             // 6250

  // ---- CSR build (once; reused by all 3 layers)
  hipMemsetAsync(cursor, 0, N_NODES * sizeof(int), stream);
  csr_count<<<EDGE_GRID, 256, 0, stream>>>(ei, cursor);
  scan_blocks<<<NODE_GRID, 256, 0, stream>>>(cursor, bsum);
  scan_bsum<<<1, 512, 0, stream>>>(bsum, NODE_GRID);
  add_offsets<<<NODE_GRID, 256, 0, stream>>>(cursor, bsum, row_ptr);
  csr_fill<<<EDGE_GRID, 256, 0, stream>>>(ei, ew, cursor, srcs, wcsr);

  // ---- layer 1
  gemm_nk128<<<GEMM_GRID, 256, 0, stream>>>(x, W1, B0);
  gather_agg<<<AGG_GRID, 256, 0, stream>>>(B0, row_ptr, srcs, wcsr, b1, B1);
  hipMemsetAsync(sums, 0, 256 * sizeof(float), stream);
  bn_stats<<<BN_GRID, 256, 0, stream>>>(B1, sums);
  bn_relu_dropout<<<APPLY_GRID, 256, 0, stream>>>(B1, sums, g1, bt1, B2, B0, k1_0, k1_1);
  // ---- layer 2
  gemm_nk128<<<GEMM_GRID, 256, 0, stream>>>(B0, W2, B1);
  gather_agg<<<AGG_GRID, 256, 0, stream>>>(B1, row_ptr, srcs, wcsr, b2, B0);
  hipMemsetAsync(sums, 0, 256 * sizeof(float), stream);
  bn_stats<<<BN_GRID, 256, 0, stream>>>(B0, sums);
  bn_relu_dropout<<<APPLY_GRID, 256, 0, stream>>>(B0, sums, g2, bt2, B3, B1, k2_0, k2_1);
  // ---- layer 3
  gemm_nk128<<<GEMM_GRID, 256, 0, stream>>>(B1, W3, B0);
  gather_agg<<<AGG_GRID, 256, 0, stream>>>(B0, row_ptr, srcs, wcsr, b3, B1);
  // ---- JK max + final linear + log_softmax
  jk_final<<<FINAL_GRID, 256, 0, stream>>>(B2, B3, B1, Wf, bfb, out);
}

// Round 4
// 600.278 us; speedup vs baseline: 5.7287x; 1.0098x over previous
//
#include <hip/hip_runtime.h>
#include <stdint.h>

#define N_NODES 100000
#define N_EDGES 600000
#define HID 128
#define OUT_C 64
#define NELEMS 12800000      // 100000*128
#define BN_EPS 1e-5f

// ---------------- threefry2x32 (matches JAX) ----------------
__device__ __host__ __forceinline__ void threefry2x32(uint32_t k0, uint32_t k1,
                                                      uint32_t x0, uint32_t x1,
                                                      uint32_t& o0, uint32_t& o1) {
  uint32_t ks0 = k0, ks1 = k1, ks2 = k0 ^ k1 ^ 0x1BD11BDAu;
  x0 += ks0; x1 += ks1;
#define TFR(r) { x0 += x1; x1 = (x1 << (r)) | (x1 >> (32 - (r))); x1 ^= x0; }
  TFR(13) TFR(15) TFR(26) TFR(6)
  x0 += ks1; x1 += ks2 + 1u;
  TFR(17) TFR(29) TFR(16) TFR(24)
  x0 += ks2; x1 += ks0 + 2u;
  TFR(13) TFR(15) TFR(26) TFR(6)
  x0 += ks0; x1 += ks1 + 3u;
  TFR(17) TFR(29) TFR(16) TFR(24)
  x0 += ks1; x1 += ks2 + 4u;
  TFR(13) TFR(15) TFR(26) TFR(6)
  x0 += ks2; x1 += ks0 + 5u;
#undef TFR
  o0 = x0; o1 = x1;
}

// JAX threefry_partitionable random_bits for flat index i: out0^out1 of threefry(key,(0,i))
__device__ __forceinline__ uint32_t jax_bits32(uint32_t k0, uint32_t k1, uint32_t i) {
  uint32_t b0, b1;
  threefry2x32(k0, k1, 0u, i, b0, b1);
  return b0 ^ b1;
}

// ---------------- plain GEMM (layer 1): O[r][c] = sum_k A[r][k]*W[k][c]
__global__ __launch_bounds__(256) void gemm_nk128(const float* __restrict__ A,
                                                  const float* __restrict__ W,
                                                  float* __restrict__ O) {
  __shared__ __align__(16) float Wl[64 * 128];
  __shared__ __align__(16) float At[64 * 36];
  const int tid = threadIdx.x;
  const int lane = tid & 63;
  const int wv = tid >> 6;
  const int rbase = blockIdx.x * 32;
  const int r0 = wv * 8;

  float acc0[8], acc1[8];
#pragma unroll
  for (int i = 0; i < 8; ++i) { acc0[i] = 0.f; acc1[i] = 0.f; }

  for (int kh = 0; kh < 2; ++kh) {
    const float4* Wsrc = (const float4*)(W + kh * 64 * 128);
    float4* Wd = (float4*)Wl;
#pragma unroll
    for (int i = 0; i < 8; ++i) Wd[tid + i * 256] = Wsrc[tid + i * 256];
#pragma unroll
    for (int i = 0; i < 2; ++i) {
      int f4 = tid + i * 256;
      int row = f4 >> 4;
      int kq = f4 & 15;
      float4 v = *(const float4*)(A + (size_t)(rbase + row) * 128 + kh * 64 + kq * 4);
      At[(kq * 4 + 0) * 36 + row] = v.x;
      At[(kq * 4 + 1) * 36 + row] = v.y;
      At[(kq * 4 + 2) * 36 + row] = v.z;
      At[(kq * 4 + 3) * 36 + row] = v.w;
    }
    __syncthreads();
#pragma unroll 4
    for (int k = 0; k < 64; ++k) {
      float4 alo = *(const float4*)&At[k * 36 + r0];
      float4 ahi = *(const float4*)&At[k * 36 + r0 + 4];
      float2 w = *(const float2*)&Wl[k * 128 + lane * 2];
      acc0[0] += alo.x * w.x; acc1[0] += alo.x * w.y;
      acc0[1] += alo.y * w.x; acc1[1] += alo.y * w.y;
      acc0[2] += alo.z * w.x; acc1[2] += alo.z * w.y;
      acc0[3] += alo.w * w.x; acc1[3] += alo.w * w.y;
      acc0[4] += ahi.x * w.x; acc1[4] += ahi.x * w.y;
      acc0[5] += ahi.y * w.x; acc1[5] += ahi.y * w.y;
      acc0[6] += ahi.z * w.x; acc1[6] += ahi.z * w.y;
      acc0[7] += ahi.w * w.x; acc1[7] += ahi.w * w.y;
    }
    __syncthreads();
  }
#pragma unroll
  for (int i = 0; i < 8; ++i) {
    int row = rbase + r0 + i;
    float2 v = make_float2(acc0[i], acc1[i]);
    *(float2*)(O + (size_t)row * 128 + lane * 2) = v;
  }
}

// ---------------- fused GEMM (layers 2,3): A-staging applies BN+ReLU (writes X)
// then dropout (threefry) and uses the dropped values as the GEMM A operand.
__global__ __launch_bounds__(256) void gemm_fused(const float* __restrict__ AGG,
                                                  const float* __restrict__ sums,
                                                  const float* __restrict__ g,
                                                  const float* __restrict__ bt,
                                                  const float* __restrict__ W,
                                                  float* __restrict__ X,
                                                  float* __restrict__ O,
                                                  uint32_t k0, uint32_t k1) {
  __shared__ __align__(16) float Wl[64 * 128];
  __shared__ __align__(16) float At[64 * 36];
  const int tid = threadIdx.x;
  const int lane = tid & 63;
  const int wv = tid >> 6;
  const int rbase = blockIdx.x * 32;
  const int r0 = wv * 8;

  float acc0[8], acc1[8];
#pragma unroll
  for (int i = 0; i < 8; ++i) { acc0[i] = 0.f; acc1[i] = 0.f; }

  for (int kh = 0; kh < 2; ++kh) {
    const float4* Wsrc = (const float4*)(W + kh * 64 * 128);
    float4* Wd = (float4*)Wl;
#pragma unroll
    for (int i = 0; i < 8; ++i) Wd[tid + i * 256] = Wsrc[tid + i * 256];
#pragma unroll
    for (int i = 0; i < 2; ++i) {
      int f4 = tid + i * 256;
      int row = f4 >> 4;
      int kq = f4 & 15;
      int c0 = kh * 64 + kq * 4;
      int grow = rbase + row;
      float4 a = *(const float4*)(AGG + (size_t)grow * 128 + c0);
      float y[4], hd[4];
#pragma unroll
      for (int jj = 0; jj < 4; ++jj) {
        int c = c0 + jj;
        float mu = sums[c] * (1.0f / N_NODES);
        float var = fmaxf(sums[128 + c] * (1.0f / N_NODES) - mu * mu, 0.f);
        float inv = rsqrtf(var + BN_EPS);
        float av = ((const float*)&a)[jj];
        float yv = fmaxf(g[c] * (av - mu) * inv + bt[c], 0.f);
        uint32_t bits = jax_bits32(k0, k1, (uint32_t)(grow * 128 + c));
        y[jj] = yv;
        hd[jj] = (bits & 0x80000000u) ? 0.f : 2.f * yv;
      }
      *(float4*)(X + (size_t)grow * 128 + c0) = *(float4*)y;
      At[(c0 - kh * 64 + 0) * 36 + row] = hd[0];
      At[(c0 - kh * 64 + 1) * 36 + row] = hd[1];
      At[(c0 - kh * 64 + 2) * 36 + row] = hd[2];
      At[(c0 - kh * 64 + 3) * 36 + row] = hd[3];
    }
    __syncthreads();
#pragma unroll 4
    for (int k = 0; k < 64; ++k) {
      float4 alo = *(const float4*)&At[k * 36 + r0];
      float4 ahi = *(const float4*)&At[k * 36 + r0 + 4];
      float2 w = *(const float2*)&Wl[k * 128 + lane * 2];
      acc0[0] += alo.x * w.x; acc1[0] += alo.x * w.y;
      acc0[1] += alo.y * w.x; acc1[1] += alo.y * w.y;
      acc0[2] += alo.z * w.x; acc1[2] += alo.z * w.y;
      acc0[3] += alo.w * w.x; acc1[3] += alo.w * w.y;
      acc0[4] += ahi.x * w.x; acc1[4] += ahi.x * w.y;
      acc0[5] += ahi.y * w.x; acc1[5] += ahi.y * w.y;
      acc0[6] += ahi.z * w.x; acc1[6] += ahi.z * w.y;
      acc0[7] += ahi.w * w.x; acc1[7] += ahi.w * w.y;
    }
    __syncthreads();
  }
#pragma unroll
  for (int i = 0; i < 8; ++i) {
    int row = rbase + r0 + i;
    float2 v = make_float2(acc0[i], acc1[i]);
    *(float2*)(O + (size_t)row * 128 + lane * 2) = v;
  }
}

// ---------------- CSR build ----------------
__global__ __launch_bounds__(256) void csr_count(const int* __restrict__ ei,
                                                 int* __restrict__ cnt) {
  int e = blockIdx.x * 256 + threadIdx.x;
  if (e < N_EDGES) atomicAdd(&cnt[ei[e + N_EDGES]], 1);
}

__global__ __launch_bounds__(256) void scan_blocks(int* __restrict__ cnt,
                                                   int* __restrict__ bsum) {
  __shared__ int tmp[256];
  int tid = threadIdx.x;
  int i = blockIdx.x * 256 + tid;
  int v = (i < N_NODES) ? cnt[i] : 0;
  tmp[tid] = v;
  __syncthreads();
  for (int off = 1; off < 256; off <<= 1) {
    int t = (tid >= off) ? tmp[tid - off] : 0;
    __syncthreads();
    if (tid >= off) tmp[tid] += t;
    __syncthreads();
  }
  if (i < N_NODES) cnt[i] = tmp[tid] - v;
  if (tid == 255) bsum[blockIdx.x] = tmp[255];
}

__global__ __launch_bounds__(512) void scan_bsum(int* __restrict__ bsum, int nb) {
  __shared__ int tmp[512];
  int tid = threadIdx.x;
  int v = (tid < nb) ? bsum[tid] : 0;
  tmp[tid] = v;
  __syncthreads();
  for (int off = 1; off < 512; off <<= 1) {
    int t = (tid >= off) ? tmp[tid - off] : 0;
    __syncthreads();
    if (tid >= off) tmp[tid] += t;
    __syncthreads();
  }
  if (tid < nb) bsum[tid] = tmp[tid] - v;
}

__global__ __launch_bounds__(256) void add_offsets(int* __restrict__ cnt,
                                                   const int* __restrict__ bsum,
                                                   int* __restrict__ row_ptr) {
  int i = blockIdx.x * 256 + threadIdx.x;
  if (i < N_NODES) {
    int r = cnt[i] + bsum[blockIdx.x];
    row_ptr[i] = r;
    cnt[i] = r;
  }
  if (i == 0) row_ptr[N_NODES] = N_EDGES;
}

__global__ __launch_bounds__(256) void csr_fill(const int* __restrict__ ei,
                                                const float* __restrict__ ew,
                                                int* __restrict__ cursor,
                                                int* __restrict__ srcs,
                                                float* __restrict__ wcsr) {
  int e = blockIdx.x * 256 + threadIdx.x;
  if (e < N_EDGES) {
    int d = ei[e + N_EDGES];
    int p = atomicAdd(&cursor[d], 1);
    srcs[p] = ei[e];
    wcsr[p] = ew[e];
  }
}

// ---------------- gather aggregation + optional fused per-channel BN stats
// grid-stride over nodes; one wave per node; lane owns channels {2l, 2l+1}
template <bool STATS>
__global__ __launch_bounds__(256) void gather_agg(const float* __restrict__ H,
                                                  const int* __restrict__ row_ptr,
                                                  const int* __restrict__ srcs,
                                                  const float* __restrict__ wcsr,
                                                  const float* __restrict__ bias,
                                                  float* __restrict__ AGG,
                                                  float* __restrict__ sums) {
  int lane = threadIdx.x & 63;
  int wv = threadIdx.x >> 6;
  float2 bv = *(const float2*)(bias + lane * 2);
  float s0 = 0.f, s1 = 0.f, q0 = 0.f, q1 = 0.f;
  for (int base = blockIdx.x * 4; base < N_NODES; base += gridDim.x * 4) {
    int node = base + wv;
    if (node < N_NODES) {
      int beg = row_ptr[node];
      int end = row_ptr[node + 1];
      float2 acc = bv;
      int j = beg;
      for (; j + 1 < end; j += 2) {
        int sA = srcs[j], sB = srcs[j + 1];
        float wA = wcsr[j], wB = wcsr[j + 1];
        float2 vA = *(const float2*)(H + (size_t)sA * 128 + lane * 2);
        float2 vB = *(const float2*)(H + (size_t)sB * 128 + lane * 2);
        acc.x += wA * vA.x + wB * vB.x;
        acc.y += wA * vA.y + wB * vB.y;
      }
      if (j < end) {
        int s = srcs[j];
        float w = wcsr[j];
        float2 v = *(const float2*)(H + (size_t)s * 128 + lane * 2);
        acc.x += w * v.x;
        acc.y += w * v.y;
      }
      *(float2*)(AGG + (size_t)node * 128 + lane * 2) = acc;
      if (STATS) {
        s0 += acc.x; s1 += acc.y;
        q0 += acc.x * acc.x; q1 += acc.y * acc.y;
      }
    }
  }
  if (STATS) {
    __shared__ float ls[4][128], lq[4][128];
    ls[wv][lane * 2] = s0; ls[wv][lane * 2 + 1] = s1;
    lq[wv][lane * 2] = q0; lq[wv][lane * 2 + 1] = q1;
    __syncthreads();
    int t = threadIdx.x;
    if (t < 128) {
      unsafeAtomicAdd(&sums[t], ls[0][t] + ls[1][t] + ls[2][t] + ls[3][t]);
    } else {
      int c = t - 128;
      unsafeAtomicAdd(&sums[t], lq[0][c] + lq[1][c] + lq[2][c] + lq[3][c]);
    }
  }
}

// ---------------- jk = max(x1,x2,x3); OUT = log_softmax(jk @ Wf + bf)
__global__ __launch_bounds__(256) void jk_final(const float* __restrict__ X1,
                                                const float* __restrict__ X2,
                                                const float* __restrict__ X3,
                                                const float* __restrict__ Wf,
                                                const float* __restrict__ bf,
                                                float* __restrict__ OUT) {
  __shared__ __align__(16) float Wl[128 * 64];
  __shared__ __align__(16) float Jl[16][128];
  int tid = threadIdx.x;
  int lane = tid & 63;
  int wv = tid >> 6;
  int rbase = blockIdx.x * 16;
  {
    const float4* ws = (const float4*)Wf;
    float4* wd = (float4*)Wl;
#pragma unroll
    for (int i = 0; i < 8; ++i) wd[tid + i * 256] = ws[tid + i * 256];
  }
#pragma unroll
  for (int i = 0; i < 2; ++i) {
    int f4 = tid + i * 256;
    int row = f4 >> 5;
    int q = f4 & 31;
    size_t off = (size_t)(rbase + row) * 128 + q * 4;
    float4 a = *(const float4*)(X1 + off);
    float4 b = *(const float4*)(X2 + off);
    float4 c = *(const float4*)(X3 + off);
    float4 m;
    m.x = fmaxf(fmaxf(a.x, b.x), c.x);
    m.y = fmaxf(fmaxf(a.y, b.y), c.y);
    m.z = fmaxf(fmaxf(a.z, b.z), c.z);
    m.w = fmaxf(fmaxf(a.w, b.w), c.w);
    *(float4*)&Jl[row][q * 4] = m;
  }
  __syncthreads();
  float acc[4];
  float bv = bf[lane];
#pragma unroll
  for (int j = 0; j < 4; ++j) acc[j] = bv;
#pragma unroll 4
  for (int k = 0; k < 128; k += 4) {
    float4 j0 = *(const float4*)&Jl[wv][k];
    float4 j1 = *(const float4*)&Jl[wv + 4][k];
    float4 j2 = *(const float4*)&Jl[wv + 8][k];
    float4 j3 = *(const float4*)&Jl[wv + 12][k];
#pragma unroll
    for (int kk = 0; kk < 4; ++kk) {
      float w = Wl[(k + kk) * 64 + lane];
      acc[0] += ((const float*)&j0)[kk] * w;
      acc[1] += ((const float*)&j1)[kk] * w;
      acc[2] += ((const float*)&j2)[kk] * w;
      acc[3] += ((const float*)&j3)[kk] * w;
    }
  }
#pragma unroll
  for (int j = 0; j < 4; ++j) {
    float v = acc[j];
    float m = v;
#pragma unroll
    for (int s = 32; s > 0; s >>= 1) m = fmaxf(m, __shfl_xor(m, s));
    float e = expf(v - m);
    float sum = e;
#pragma unroll
    for (int s = 32; s > 0; s >>= 1) sum += __shfl_xor(sum, s);
    OUT[(size_t)(rbase + wv + 4 * j) * 64 + lane] = v - m - logf(sum);
  }
}

extern "C" void kernel_launch(void* const* d_in, const int* in_sizes, int n_in,
                              void* d_out, int out_size, void* d_ws, size_t ws_size,
                              hipStream_t stream) {
  const float* x   = (const float*)d_in[0];
  const int*   ei  = (const int*)d_in[1];
  const float* ew  = (const float*)d_in[2];
  const float* W1  = (const float*)d_in[3];
  const float* b1  = (const float*)d_in[4];
  const float* W2  = (const float*)d_in[5];
  const float* b2  = (const float*)d_in[6];
  const float* W3  = (const float*)d_in[7];
  const float* b3  = (const float*)d_in[8];
  const float* g1  = (const float*)d_in[9];
  const float* bt1 = (const float*)d_in[10];
  const float* g2  = (const float*)d_in[11];
  const float* bt2 = (const float*)d_in[12];
  const float* Wf  = (const float*)d_in[13];
  const float* bfb = (const float*)d_in[14];
  float* out = (float*)d_out;

  float* B0 = (float*)d_ws;
  float* B1 = B0 + NELEMS;
  float* B2 = B1 + NELEMS;
  float* B3 = B2 + NELEMS;
  float* sums = B3 + NELEMS;               // 512 floats: [0..255]=layer1, [256..511]=layer2
  int* cursor = (int*)(sums + 512);        // N_NODES
  int* row_ptr = cursor + N_NODES;         // N_NODES+1
  int* bsum = row_ptr + N_NODES + 1;       // 512
  int* srcs = bsum + 512;                  // N_EDGES
  float* wcsr = (float*)(srcs + N_EDGES);  // N_EDGES
  float* sums1 = sums;
  float* sums2 = sums + 256;

  // JAX partitionable split of key(42)=(0,42): k_i = threefry(key, (0,i)) full pair
  uint32_t k1_0, k1_1, k2_0, k2_1;
  threefry2x32(0u, 42u, 0u, 0u, k1_0, k1_1);
  threefry2x32(0u, 42u, 0u, 1u, k2_0, k2_1);

  const int GEMM_GRID = N_NODES / 32;              // 3125
  const int EDGE_GRID = (N_EDGES + 255) / 256;     // 2344
  const int NODE_GRID = (N_NODES + 255) / 256;     // 391
  const int AGG_GRID  = 2048;                      // grid-stride
  const int FINAL_GRID = N_NODES / 16;             // 6250

  // ---- CSR build (reused by all 3 layers)
  hipMemsetAsync(cursor, 0, N_NODES * sizeof(int), stream);
  hipMemsetAsync(sums, 0, 512 * sizeof(float), stream);
  csr_count<<<EDGE_GRID, 256, 0, stream>>>(ei, cursor);
  scan_blocks<<<NODE_GRID, 256, 0, stream>>>(cursor, bsum);
  scan_bsum<<<1, 512, 0, stream>>>(bsum, NODE_GRID);
  add_offsets<<<NODE_GRID, 256, 0, stream>>>(cursor, bsum, row_ptr);
  csr_fill<<<EDGE_GRID, 256, 0, stream>>>(ei, ew, cursor, srcs, wcsr);

  // ---- layer 1: P1 = x@W1 ; AGG1 = gather(P1)+b1 (stats1)
  gemm_nk128<<<GEMM_GRID, 256, 0, stream>>>(x, W1, B0);
  gather_agg<true><<<AGG_GRID, 256, 0, stream>>>(B0, row_ptr, srcs, wcsr, b1, B1, sums1);
  // ---- layer 2: fused BN1+ReLU (-> X1=B2) + dropout(k1) + GEMM W2 -> P2=B0
  gemm_fused<<<GEMM_GRID, 256, 0, stream>>>(B1, sums1, g1, bt1, W2, B2, B0, k1_0, k1_1);
  gather_agg<true><<<AGG_GRID, 256, 0, stream>>>(B0, row_ptr, srcs, wcsr, b2, B1, sums2);
  // ---- layer 3: fused BN2+ReLU (-> X2=B3) + dropout(k2) + GEMM W3 -> P3=B0
  gemm_fused<<<GEMM_GRID, 256, 0, stream>>>(B1, sums2, g2, bt2, W3, B3, B0, k2_0, k2_1);
  gather_agg<false><<<AGG_GRID, 256, 0, stream>>>(B0, row_ptr, srcs, wcsr, b3, B1, nullptr);
  // ---- JK max + final linear + log_softmax
  jk_final<<<FINAL_GRID, 256, 0, stream>>>(B2, B3, B1, Wf, bfb, out);
}